// Round 1
// baseline (3276.594 us; speedup 1.0000x reference)
//
#include <hip/hip_runtime.h>

#define N_NODES 100000
#define N_EDGES 3200000
#define N_GRAPHS 1024
#define HID 64
#define NCLS 21

// ---------------- Layer 1: edge scatter (scalar features) ----------------
__global__ void k_edge1(const int* __restrict__ src, const int* __restrict__ dst,
                        const float* __restrict__ x,
                        float* __restrict__ agg1, float* __restrict__ cnt) {
    int e = blockIdx.x * blockDim.x + threadIdx.x;
    if (e < N_EDGES) {
        int s = src[e];
        int d = dst[e];
        atomicAdd(&agg1[d], x[s]);
        atomicAdd(&cnt[d], 1.0f);
    }
}

// ---------------- Layer 1: node update -> h1 [N,64] ----------------
__global__ void k_node1(const float* __restrict__ agg1, const float* __restrict__ cnt,
                        const float* __restrict__ x,
                        const float* __restrict__ W1l, const float* __restrict__ b1,
                        const float* __restrict__ W1r,
                        const int* __restrict__ batch, float* __restrict__ gcnt,
                        float* __restrict__ h1) {
    int t = blockIdx.x * blockDim.x + threadIdx.x;
    int n = t >> 6;
    int f = t & 63;
    if (n >= N_NODES) return;
    float a = agg1[n] / fmaxf(cnt[n], 1.0f);   // broadcast loads across the wave
    float v = a * W1l[f] + b1[f] + x[n] * W1r[f];
    h1[n * 64 + f] = fmaxf(v, 0.0f);
    if (f == 0) atomicAdd(&gcnt[batch[n]], 1.0f);
}

// ---------------- Layer 2: edge scatter (64 features) — THE HOT KERNEL ----------------
// 16 threads per edge; each thread moves one float4 (16B). Gather from h1[src] is a
// coalesced 256B read per edge (h1 is 25.6MB -> L2/L3 resident); scatter is 4 f32
// atomics per thread to contiguous addresses of agg2[dst].
__global__ void k_edge2(const int* __restrict__ src, const int* __restrict__ dst,
                        const float* __restrict__ h1, float* __restrict__ agg2) {
    int t = blockIdx.x * 256 + threadIdx.x;   // grid sized exactly: E*16 threads
    int e = t >> 4;
    int q = t & 15;
    int s = src[e];
    int d = dst[e];
    const float4 v = *(const float4*)(h1 + (size_t)s * 64 + q * 4);
    float* p = agg2 + (size_t)d * 64 + q * 4;
    atomicAdd(p + 0, v.x);
    atomicAdd(p + 1, v.y);
    atomicAdd(p + 2, v.z);
    atomicAdd(p + 3, v.w);
}

// ---------------- Layer 2 node update + fused mean-pool ----------------
// lane f owns output feature f. W2 columns live in registers (128 VGPR);
// row elements broadcast via v_readlane (VALU pipe, keeps LDS idle).
__global__ __launch_bounds__(256) void k_node2(
    const float* __restrict__ agg2, const float* __restrict__ h1,
    const float* __restrict__ cnt,
    const float* __restrict__ W2l, const float* __restrict__ b2,
    const float* __restrict__ W2r,
    const int* __restrict__ batch, const float* __restrict__ gcnt,
    float* __restrict__ pooled) {
    int f = threadIdx.x & 63;
    int w = threadIdx.x >> 6;

    float wl[64], wr[64];
#pragma unroll
    for (int k = 0; k < 64; k++) {
        wl[k] = W2l[k * 64 + f];   // coalesced: lane f reads consecutive addrs
        wr[k] = W2r[k * 64 + f];
    }
    float bias = b2[f];

    for (int n = blockIdx.x * 4 + w; n < N_NODES; n += gridDim.x * 4) {
        float m = agg2[n * 64 + f] / fmaxf(cnt[n], 1.0f);
        float h = h1[n * 64 + f];
        float acc = bias;
#pragma unroll
        for (int k = 0; k < 64; k++) {
            acc += __int_as_float(__builtin_amdgcn_readlane(__float_as_int(m), k)) * wl[k];
            acc += __int_as_float(__builtin_amdgcn_readlane(__float_as_int(h), k)) * wr[k];
        }
        acc = fmaxf(acc, 0.0f);   // relu(h2)
        int b = batch[n];
        float rg = 1.0f / fmaxf(gcnt[b], 1.0f);
        atomicAdd(&pooled[b * 64 + f], acc * rg);
    }
}

// ---------------- classifier: pooled[1024,64] @ Wc[64,21] + bc ----------------
__global__ void k_cls(const float* __restrict__ pooled, const float* __restrict__ Wc,
                      const float* __restrict__ bc, float* __restrict__ out) {
    __shared__ float row[64];
    int g = blockIdx.x;
    int f = threadIdx.x;
    row[f] = pooled[g * 64 + f];
    __syncthreads();
    if (f < NCLS) {
        float acc = bc[f];
#pragma unroll
        for (int k = 0; k < 64; k++) acc += row[k] * Wc[k * NCLS + f];
        out[g * NCLS + f] = acc;
    }
}

extern "C" void kernel_launch(void* const* d_in, const int* in_sizes, int n_in,
                              void* d_out, int out_size, void* d_ws, size_t ws_size,
                              hipStream_t stream) {
    const float* x      = (const float*)d_in[0];
    const int*   eidx   = (const int*)d_in[1];       // [2, E] flat: src row then dst row
    const int*   batch  = (const int*)d_in[2];
    const float* W1l    = (const float*)d_in[3];
    const float* b1     = (const float*)d_in[4];
    const float* W1r    = (const float*)d_in[5];
    const float* W2l    = (const float*)d_in[6];
    const float* b2     = (const float*)d_in[7];
    const float* W2r    = (const float*)d_in[8];
    const float* Wc     = (const float*)d_in[9];
    const float* bc     = (const float*)d_in[10];
    float* out = (float*)d_out;

    const int* src = eidx;
    const int* dst = eidx + N_EDGES;

    // workspace layout (floats)
    float* ws     = (float*)d_ws;
    float* agg1   = ws;                                  // N
    float* cnt    = ws + N_NODES;                        // N
    float* gcnt   = ws + 2 * N_NODES;                    // 1024
    float* pooled = ws + 2 * N_NODES + N_GRAPHS;         // 1024*64
    float* h1     = ws + 2 * N_NODES + N_GRAPHS + N_GRAPHS * 64;  // N*64 (16B aligned)
    float* agg2   = h1 + (size_t)N_NODES * 64;                    // N*64

    // zero the accumulated regions (h1 is fully overwritten, skip it)
    size_t zero1 = (size_t)(2 * N_NODES + N_GRAPHS + N_GRAPHS * 64) * sizeof(float);
    hipMemsetAsync(ws, 0, zero1, stream);
    hipMemsetAsync(agg2, 0, (size_t)N_NODES * 64 * sizeof(float), stream);

    k_edge1<<<(N_EDGES + 255) / 256, 256, 0, stream>>>(src, dst, x, agg1, cnt);

    k_node1<<<(N_NODES * 64) / 256, 256, 0, stream>>>(agg1, cnt, x, W1l, b1, W1r,
                                                      batch, gcnt, h1);

    k_edge2<<<(N_EDGES * 16) / 256, 256, 0, stream>>>(src, dst, h1, agg2);

    k_node2<<<2048, 256, 0, stream>>>(agg2, h1, cnt, W2l, b2, W2r, batch, gcnt, pooled);

    k_cls<<<N_GRAPHS, 64, 0, stream>>>(pooled, Wc, bc, out);
}

// Round 2
// 820.887 us; speedup vs baseline: 3.9915x; 3.9915x over previous
//
#include <hip/hip_runtime.h>

#define N_NODES 100000
#define N_EDGES 3200000
#define N_GRAPHS 1024
#define HID 64
#define NCLS 21
#define SCAN_NB 98   // ceil(100000/1024)

__device__ __forceinline__ float rlanef(float v, int l) {
    return __int_as_float(__builtin_amdgcn_readlane(__float_as_int(v), l));
}

// ---- CSR build step 1: degree histogram (3.2M int atomics, 100k bins) ----
__global__ void k_deg(const int* __restrict__ dst, int* __restrict__ deg) {
    int e = blockIdx.x * 256 + threadIdx.x;
    if (e < N_EDGES) atomicAdd(&deg[dst[e]], 1);
}

// ---- scan 1: per-block (1024 elems) exclusive scan + block sums ----
__global__ void k_scan1(const int* __restrict__ deg, int* __restrict__ partial,
                        int* __restrict__ bsum) {
    __shared__ int lds[256];
    int t = threadIdx.x;
    int base = blockIdx.x * 1024 + t * 4;
    int v[4];
#pragma unroll
    for (int i = 0; i < 4; i++) v[i] = (base + i < N_NODES) ? deg[base + i] : 0;
    int tsum = v[0] + v[1] + v[2] + v[3];
    lds[t] = tsum;
    __syncthreads();
    for (int off = 1; off < 256; off <<= 1) {
        int cur = lds[t];
        int add = (t >= off) ? lds[t - off] : 0;
        __syncthreads();
        lds[t] = cur + add;
        __syncthreads();
    }
    int run = lds[t] - tsum;   // exclusive start for this thread
#pragma unroll
    for (int i = 0; i < 4; i++) {
        if (base + i < N_NODES) partial[base + i] = run;
        run += v[i];
    }
    if (t == 255) bsum[blockIdx.x] = lds[255];
}

// ---- scan 2: exclusive scan of the 98 block sums (serial, tiny) ----
__global__ void k_scan2(int* __restrict__ bsum) {
    if (threadIdx.x == 0 && blockIdx.x == 0) {
        int acc = 0;
        for (int b = 0; b < SCAN_NB; b++) { int t = bsum[b]; bsum[b] = acc; acc += t; }
    }
}

// ---- scan 3: combine -> row[], init cursor[] ----
__global__ void k_scan3(const int* __restrict__ partial, const int* __restrict__ bsum,
                        int* __restrict__ row, int* __restrict__ cursor) {
    int i = blockIdx.x * 256 + threadIdx.x;
    if (i < N_NODES) {
        int r = partial[i] + bsum[i >> 10];
        row[i] = r;
        cursor[i] = r;
    }
    if (i == 0) row[N_NODES] = N_EDGES;
}

// ---- CSR build step 2: scatter src into csr, bucketed by dst ----
__global__ void k_scatter(const int* __restrict__ src, const int* __restrict__ dst,
                          int* __restrict__ cursor, int* __restrict__ csr) {
    int e = blockIdx.x * 256 + threadIdx.x;
    if (e < N_EDGES) {
        int pos = atomicAdd(&cursor[dst[e]], 1);
        csr[pos] = src[e];
    }
}

// ---- layer 1 fused: per-node wave gathers x[src], reduces, linear+relu -> h1 ----
__global__ __launch_bounds__(256) void k_node1(
    const int* __restrict__ row, const int* __restrict__ csr,
    const float* __restrict__ x,
    const float* __restrict__ W1l, const float* __restrict__ b1,
    const float* __restrict__ W1r,
    const int* __restrict__ batch, float* __restrict__ gcnt,
    float* __restrict__ h1) {
    int n = (blockIdx.x * 256 + threadIdx.x) >> 6;   // 4 waves/block, 1 node/wave
    int f = threadIdx.x & 63;
    if (n >= N_NODES) return;
    int r0 = row[n], r1 = row[n + 1];
    float s = 0.0f;
    for (int idx = r0 + f; idx < r1; idx += 64) s += x[csr[idx]];
#pragma unroll
    for (int off = 32; off; off >>= 1) s += __shfl_xor(s, off);
    float agg = s / fmaxf((float)(r1 - r0), 1.0f);
    float v = agg * W1l[f] + b1[f] + x[n] * W1r[f];
    h1[(size_t)n * 64 + f] = fmaxf(v, 0.0f);
    if (f == 0) atomicAdd(&gcnt[batch[n]], 1.0f);
}

// ---- layer 2 fused: aggregate h1[src] (no atomics) + W2 GEMV + relu + pool ----
// Persistent waves: weights live in 128 VGPRs, loaded once per wave.
__global__ __launch_bounds__(256) void k_node2(
    const int* __restrict__ row, const int* __restrict__ csr,
    const float* __restrict__ h1,
    const float* __restrict__ W2l, const float* __restrict__ b2,
    const float* __restrict__ W2r,
    const int* __restrict__ batch, const float* __restrict__ gcnt,
    float* __restrict__ pooled) {
    int gw = (blockIdx.x * 256 + threadIdx.x) >> 6;
    int nwaves = gridDim.x * 4;
    int f = threadIdx.x & 63;

    float wl[64], wr[64];
#pragma unroll
    for (int k = 0; k < 64; k++) {
        wl[k] = W2l[k * 64 + f];
        wr[k] = W2r[k * 64 + f];
    }
    float bias = b2[f];

    for (int n = gw; n < N_NODES; n += nwaves) {
        int r0 = row[n], r1 = row[n + 1];
        float s = 0.0f;
        for (int base = r0; base < r1; base += 64) {
            int idx = base + f;
            int vsrc = (idx < r1) ? csr[idx] : 0;
            int c = min(64, r1 - base);
            int j = 0;
            for (; j + 8 <= c; j += 8) {   // 8 independent gathers in flight
                float t0 = h1[(size_t)__builtin_amdgcn_readlane(vsrc, j + 0) * 64 + f];
                float t1 = h1[(size_t)__builtin_amdgcn_readlane(vsrc, j + 1) * 64 + f];
                float t2 = h1[(size_t)__builtin_amdgcn_readlane(vsrc, j + 2) * 64 + f];
                float t3 = h1[(size_t)__builtin_amdgcn_readlane(vsrc, j + 3) * 64 + f];
                float t4 = h1[(size_t)__builtin_amdgcn_readlane(vsrc, j + 4) * 64 + f];
                float t5 = h1[(size_t)__builtin_amdgcn_readlane(vsrc, j + 5) * 64 + f];
                float t6 = h1[(size_t)__builtin_amdgcn_readlane(vsrc, j + 6) * 64 + f];
                float t7 = h1[(size_t)__builtin_amdgcn_readlane(vsrc, j + 7) * 64 + f];
                s += ((t0 + t1) + (t2 + t3)) + ((t4 + t5) + (t6 + t7));
            }
            for (; j < c; ++j)
                s += h1[(size_t)__builtin_amdgcn_readlane(vsrc, j) * 64 + f];
        }
        float m = s / fmaxf((float)(r1 - r0), 1.0f);
        float h = h1[(size_t)n * 64 + f];
        float acc = bias;
#pragma unroll
        for (int k = 0; k < 64; k++) {
            acc += rlanef(m, k) * wl[k];
            acc += rlanef(h, k) * wr[k];
        }
        acc = fmaxf(acc, 0.0f);
        int b = batch[n];
        float rg = 1.0f / fmaxf(gcnt[b], 1.0f);
        atomicAdd(&pooled[b * 64 + f], acc * rg);
    }
}

// ---- classifier: pooled[1024,64] @ Wc[64,21] + bc ----
__global__ void k_cls(const float* __restrict__ pooled, const float* __restrict__ Wc,
                      const float* __restrict__ bc, float* __restrict__ out) {
    __shared__ float rowv[64];
    int g = blockIdx.x;
    int f = threadIdx.x;
    rowv[f] = pooled[g * 64 + f];
    __syncthreads();
    if (f < NCLS) {
        float acc = bc[f];
#pragma unroll
        for (int k = 0; k < 64; k++) acc += rowv[k] * Wc[k * NCLS + f];
        out[g * NCLS + f] = acc;
    }
}

extern "C" void kernel_launch(void* const* d_in, const int* in_sizes, int n_in,
                              void* d_out, int out_size, void* d_ws, size_t ws_size,
                              hipStream_t stream) {
    const float* x     = (const float*)d_in[0];
    const int*   eidx  = (const int*)d_in[1];
    const int*   batch = (const int*)d_in[2];
    const float* W1l   = (const float*)d_in[3];
    const float* b1    = (const float*)d_in[4];
    const float* W1r   = (const float*)d_in[5];
    const float* W2l   = (const float*)d_in[6];
    const float* b2    = (const float*)d_in[7];
    const float* W2r   = (const float*)d_in[8];
    const float* Wc    = (const float*)d_in[9];
    const float* bc    = (const float*)d_in[10];
    float* out = (float*)d_out;

    const int* src = eidx;
    const int* dst = eidx + N_EDGES;

    // workspace layout (4-byte units)
    char* p = (char*)d_ws;
    float* gcnt   = (float*)p;                       p += N_GRAPHS * 4;
    float* pooled = (float*)p;                       p += N_GRAPHS * 64 * 4;
    int*   deg    = (int*)p;                         p += N_NODES * 4;
    // ---- end of zeroed region ----
    size_t zero_bytes = (size_t)(N_GRAPHS + N_GRAPHS * 64 + N_NODES) * 4;
    int*   row    = (int*)p;                         p += (N_NODES + 1) * 4;
    int*   cursor = (int*)p;                         p += N_NODES * 4;
    int*   partial= (int*)p;                         p += N_NODES * 4;
    int*   bsum   = (int*)p;                         p += 128 * 4;
    int*   csr    = (int*)p;                         p += (size_t)N_EDGES * 4;
    float* h1     = (float*)p;                       p += (size_t)N_NODES * 64 * 4;

    hipMemsetAsync(d_ws, 0, zero_bytes, stream);

    k_deg<<<(N_EDGES + 255) / 256, 256, 0, stream>>>(dst, deg);
    k_scan1<<<SCAN_NB, 256, 0, stream>>>(deg, partial, bsum);
    k_scan2<<<1, 64, 0, stream>>>(bsum);
    k_scan3<<<(N_NODES + 255) / 256, 256, 0, stream>>>(partial, bsum, row, cursor);
    k_scatter<<<(N_EDGES + 255) / 256, 256, 0, stream>>>(src, dst, cursor, csr);

    k_node1<<<(N_NODES * 64) / 256, 256, 0, stream>>>(row, csr, x, W1l, b1, W1r,
                                                      batch, gcnt, h1);
    k_node2<<<2048, 256, 0, stream>>>(row, csr, h1, W2l, b2, W2r, batch, gcnt, pooled);
    k_cls<<<N_GRAPHS, 64, 0, stream>>>(pooled, Wc, bc, out);
}